// Round 1
// baseline (15496.193 us; speedup 1.0000x reference)
//
#include <hip/hip_runtime.h>
#include <math.h>

// ---------------------------------------------------------------------------
// MyRNN: xp = x@Wx^T+bx (WG-private precompute), then 2048 serial steps
// h = tanh(h@Wh^T + bh + xp[t]) on a persistent 256-WG grid with a flag-based
// global barrier per step, then out = sigmoid(hT@Wo^T + bo).
//
// ws layout (floats):
//   [0,      4096)  flags: 256 WGs * 16-word stride (64B padded), int
//   [4096,   8192)  hbuf0 (4096 f32)   -- h for even steps
//   [8192,  12288)  hbuf1 (4096 f32)   -- h for odd steps
//   [12288, ...  )  xp: [256][2048][16] f32 (32 MiB, WG-private slices)
// ws requirement: 48 KiB + 32 MiB.
// flags/hbuf are hipMemsetAsync'd to 0 every launch (h0 = 0, flags = 0).
// ---------------------------------------------------------------------------

#define T_STEPS  2048
#define INPUT_N  2048
#define HIDDEN_N 4096
#define NWG      256
#define NTHR     1024
#define FLAG_STRIDE 16   // ints; 64B per flag to avoid line contention

typedef float f32x4 __attribute__((ext_vector_type(4)));

__device__ __forceinline__ float wave_reduce(float v) {
#pragma unroll
  for (int off = 32; off > 0; off >>= 1) v += __shfl_xor(v, off, 64);
  return v;
}

__global__ __launch_bounds__(NTHR, 4) void rnn_persistent(
    const float* __restrict__ x,
    const float* __restrict__ wh_w, const float* __restrict__ wh_b,
    const float* __restrict__ wx_w, const float* __restrict__ wx_b,
    const float* __restrict__ wo_w, const float* __restrict__ wo_b,
    float* __restrict__ out, float* __restrict__ ws) {
  const int w    = blockIdx.x;    // 0..255, owns hidden rows [16w, 16w+16)
  const int tid  = threadIdx.x;   // 0..1023
  const int lane = tid & 63;
  const int wv   = tid >> 6;      // wave 0..15

  int*   flags = (int*)ws;
  float* hbuf0 = ws + 4096;
  float* hbuf1 = ws + 8192;
  float* xp    = ws + 12288;      // [w][t][16]

  __shared__ float s_h[HIDDEN_N];   // 16 KiB: h broadcast (also x[t] staging)
  __shared__ float s_part[16][4];
  __shared__ float s_hnew[16];

  // ------------------------- Phase A: xp (WG-private) ----------------------
  {
    const int a = wv >> 2;          // 0..3 -> rows 4a..4a+3
    const int b = wv & 3;           // col quarter (512 cols)
    f32x4 wxr[4][2];
#pragma unroll
    for (int rr = 0; rr < 4; ++rr) {
      const float* wrow =
          wx_w + (size_t)(w * 16 + a * 4 + rr) * INPUT_N + b * 512 + 4 * lane;
      wxr[rr][0] = *(const f32x4*)(wrow);
      wxr[rr][1] = *(const f32x4*)(wrow + 256);
    }
    const float biasA = (tid < 16) ? wx_b[w * 16 + tid] : 0.f;

    for (int t = 0; t < T_STEPS; ++t) {
      __syncthreads();                       // s_h / s_part reuse-safe
      if (tid < 512)
        *(f32x4*)&s_h[tid * 4] = *(const f32x4*)&x[(size_t)t * INPUT_N + tid * 4];
      __syncthreads();

      const float* hb = &s_h[b * 512 + 4 * lane];
      f32x4 xv0 = *(const f32x4*)(hb);
      f32x4 xv1 = *(const f32x4*)(hb + 256);
      float r[4];
#pragma unroll
      for (int rr = 0; rr < 4; ++rr) {
        f32x4 p = xv0 * wxr[rr][0] + xv1 * wxr[rr][1];
        r[rr] = wave_reduce(p.x + p.y + p.z + p.w);
      }
      if (lane == 0) {
#pragma unroll
        for (int rr = 0; rr < 4; ++rr) s_part[a * 4 + rr][b] = r[rr];
      }
      __syncthreads();
      if (tid < 16) {
        float v = s_part[tid][0] + s_part[tid][1] + s_part[tid][2] +
                  s_part[tid][3] + biasA;
        xp[((size_t)w * T_STEPS + t) * 16 + tid] = v;   // private: plain store
      }
    }
  }
  __syncthreads();
  if (tid == 0)   // "ready for step 0" (h0 = zeros via memset)
    __hip_atomic_store(&flags[w * FLAG_STRIDE], 1, __ATOMIC_RELEASE,
                       __HIP_MEMORY_SCOPE_AGENT);

  // ------------------------- Phase B: the scan -----------------------------
  const int a = wv >> 1;            // 0..7 -> rows 2a, 2a+1
  const int b = wv & 1;             // col half (2048 cols)
  f32x4 whr[2][8];                  // 64 f32 of Wh per thread, in VGPRs
#pragma unroll
  for (int rr = 0; rr < 2; ++rr) {
    const float* wrow =
        wh_w + (size_t)(w * 16 + a * 2 + rr) * HIDDEN_N + b * 2048 + 4 * lane;
#pragma unroll
    for (int k = 0; k < 8; ++k) whr[rr][k] = *(const f32x4*)(wrow + 256 * k);
  }
  const float biasB = (tid < 16) ? wh_b[w * 16 + tid] : 0.f;
  const float* myxp = xp + (size_t)w * T_STEPS * 16 + tid;  // tid<16 only

  int cur = 0;
  for (int t = 0; t < T_STEPS; ++t) {
    // 1) wait until every WG published h_t
    if (wv == 0) {
      const int target = t + 1;
      bool done = false;
      while (!done) {
        bool ok = true;
#pragma unroll
        for (int k = 0; k < 4; ++k) {
          int f = __hip_atomic_load(&flags[(k * 64 + lane) * FLAG_STRIDE],
                                    __ATOMIC_RELAXED, __HIP_MEMORY_SCOPE_AGENT);
          ok = ok && (f >= target);
        }
        done = __all(ok);
      }
    }
    __syncthreads();

    // 2) stage h_t -> LDS (agent-scope loads bypass stale L1/L2, hit L3)
    float* hsrc = cur ? hbuf1 : hbuf0;
#pragma unroll
    for (int k = 0; k < 4; ++k)
      s_h[tid + 1024 * k] = __hip_atomic_load(&hsrc[tid + 1024 * k],
                                              __ATOMIC_RELAXED,
                                              __HIP_MEMORY_SCOPE_AGENT);
    __syncthreads();

    // 3) 2 rows/wave dot over our col half, Wh from VGPRs
    const float* hb = &s_h[b * 2048 + 4 * lane];
    f32x4 acc0 = {0.f, 0.f, 0.f, 0.f}, acc1 = {0.f, 0.f, 0.f, 0.f};
#pragma unroll
    for (int k = 0; k < 8; ++k) {
      f32x4 hv = *(const f32x4*)(hb + 256 * k);
      acc0 += hv * whr[0][k];
      acc1 += hv * whr[1][k];
    }
    float r0 = wave_reduce(acc0.x + acc0.y + acc0.z + acc0.w);
    float r1 = wave_reduce(acc1.x + acc1.y + acc1.z + acc1.w);
    if (lane == 0) {
      s_part[a * 2 + 0][b] = r0;
      s_part[a * 2 + 1][b] = r1;
    }
    __syncthreads();

    // 4) finalize 16 rows: + bias + xp[t], tanh
    if (tid < 16) {
      float pre = s_part[tid][0] + s_part[tid][1] + biasB + myxp[(size_t)t * 16];
      s_hnew[tid] = tanhf(pre);
    }
    __syncthreads();

    // 5) publish our 16 h values + flag (single thread => ordered release)
    if (tid == 0) {
      float* hdst = cur ? hbuf0 : hbuf1;
#pragma unroll
      for (int j = 0; j < 16; ++j)
        __hip_atomic_store(&hdst[w * 16 + j], s_hnew[j], __ATOMIC_RELAXED,
                           __HIP_MEMORY_SCOPE_AGENT);
      __hip_atomic_store(&flags[w * FLAG_STRIDE], t + 2, __ATOMIC_RELEASE,
                         __HIP_MEMORY_SCOPE_AGENT);
    }
    cur ^= 1;
  }

  // ------------------------- Phase C: output -------------------------------
  if (wv == 0) {
    const int target = T_STEPS + 1;
    bool done = false;
    while (!done) {
      bool ok = true;
#pragma unroll
      for (int k = 0; k < 4; ++k) {
        int f = __hip_atomic_load(&flags[(k * 64 + lane) * FLAG_STRIDE],
                                  __ATOMIC_RELAXED, __HIP_MEMORY_SCOPE_AGENT);
        ok = ok && (f >= target);
      }
      done = __all(ok);
    }
  }
  __syncthreads();
#pragma unroll
  for (int k = 0; k < 4; ++k)     // h_T lives in hbuf0 (2048 toggles)
    s_h[tid + 1024 * k] = __hip_atomic_load(&hbuf0[tid + 1024 * k],
                                            __ATOMIC_RELAXED,
                                            __HIP_MEMORY_SCOPE_AGENT);
  __syncthreads();
  if (wv < 8) {                   // 8 outputs per WG
    const int o = w * 8 + wv;
    const float* worow = wo_w + (size_t)o * HIDDEN_N + 4 * lane;
    f32x4 acc = {0.f, 0.f, 0.f, 0.f};
#pragma unroll
    for (int k = 0; k < 16; ++k) {
      f32x4 wv4 = *(const f32x4*)(worow + 256 * k);
      f32x4 hv  = *(const f32x4*)&s_h[4 * lane + 256 * k];
      acc += wv4 * hv;
    }
    float s = wave_reduce(acc.x + acc.y + acc.z + acc.w);
    if (lane == 0) {
      float z = s + wo_b[o];
      out[o] = 1.f / (1.f + expf(-z));
    }
  }
}

extern "C" void kernel_launch(void* const* d_in, const int* in_sizes, int n_in,
                              void* d_out, int out_size, void* d_ws,
                              size_t ws_size, hipStream_t stream) {
  const float* x    = (const float*)d_in[0];
  const float* wh_w = (const float*)d_in[1];
  const float* wh_b = (const float*)d_in[2];
  const float* wx_w = (const float*)d_in[3];
  const float* wx_b = (const float*)d_in[4];
  const float* wo_w = (const float*)d_in[5];
  const float* wo_b = (const float*)d_in[6];
  float* out = (float*)d_out;
  float* ws  = (float*)d_ws;

  // flags + h double-buffer must start at 0 every call (deterministic replay)
  hipMemsetAsync(d_ws, 0, 48 * 1024, stream);

  hipLaunchKernelGGL(rnn_persistent, dim3(NWG), dim3(NTHR), 0, stream,
                     x, wh_w, wh_b, wx_w, wx_b, wo_w, wo_b, out, ws);
}